// Round 1
// baseline (65.936 us; speedup 1.0000x reference)
//
#include <hip/hip_runtime.h>
#include <cstdint>
#include <cstddef>

#define HID 128
#define A_DIM 32

// ws layout (floats):
//   [0, 128)          Wa1 = W @ a_w[:128]
//   [128, 256)        Wa2 = W @ a_w[128:]
//   [256, 256+16384)  owT[h][o] = out_w[o][h]
//   [16640, +8192*128) U[b*32+n][:] = h[b,n,:] + wm[b,n,:]
// total ~4.26 MB

__global__ void precompute_kernel(const float* __restrict__ W,
                                  const float* __restrict__ a_w,
                                  const float* __restrict__ out_w,
                                  float* __restrict__ ws) {
    int d = threadIdx.x;  // 0..127
    const float* row = W + d * HID;
    float s1 = 0.f, s2 = 0.f;
    for (int hh = 0; hh < HID; ++hh) {
        float w = row[hh];
        s1 += w * a_w[hh];
        s2 += w * a_w[HID + hh];
    }
    ws[d] = s1;
    ws[HID + d] = s2;
    float* owT = ws + 256;
    for (int o = 0; o < HID; ++o) owT[d * HID + o] = out_w[o * HID + d];
}

__global__ __launch_bounds__(256) void attn_kernel(
    const float* __restrict__ hmat,
    const float* __restrict__ message,
    const int* __restrict__ mask,
    const float* __restrict__ ws_const,  // Wa1 at +0, Wa2 at +128
    float* __restrict__ U) {
    __shared__ float msg[A_DIM][HID];  // 16 KB
    __shared__ float hv[HID];
    __shared__ float e2s[A_DIM];
    __shared__ float coef[A_DIM];
    __shared__ float e1s;

    const int tid = threadIdx.x;
    const size_t bid = blockIdx.x;  // flattened (b, n), 0..8191

    // ---- stage message[b,n,:,:] (32x128 f32) into LDS, float4-coalesced ----
    const float4* gm = reinterpret_cast<const float4*>(message + bid * (A_DIM * HID));
    float4* sm = reinterpret_cast<float4*>(&msg[0][0]);
#pragma unroll
    for (int i = 0; i < 4; ++i) sm[tid + i * 256] = gm[tid + i * 256];
    if (tid < HID) hv[tid] = hmat[bid * HID + tid];
    __syncthreads();

    const float* Wa1 = ws_const;
    const float* Wa2 = ws_const + HID;

    // ---- e1 = dot(h[b,n,:], Wa1)  (wave 0) ----
    if (tid < 64) {
        float p = hv[tid] * Wa1[tid] + hv[tid + 64] * Wa1[tid + 64];
        p += __shfl_down(p, 32, 64);
        p += __shfl_down(p, 16, 64);
        p += __shfl_down(p, 8, 64);
        p += __shfl_down(p, 4, 64);
        p += __shfl_down(p, 2, 64);
        p += __shfl_down(p, 1, 64);
        if (tid == 0) e1s = p;
    }
    // ---- e2[a] = dot(message[b,n,a,:], Wa2)  (8 threads per a) ----
    {
        const int a = tid >> 3, pp = tid & 7;
        const float* mrow = &msg[a][pp * 16];
        const float* wrow = &Wa2[pp * 16];
        float p = 0.f;
#pragma unroll
        for (int i = 0; i < 16; ++i) p += mrow[i] * wrow[i];
        p += __shfl_down(p, 4, 8);
        p += __shfl_down(p, 2, 8);
        p += __shfl_down(p, 1, 8);
        if (pp == 0) e2s[a] = p;
    }
    __syncthreads();

    // ---- leaky-relu, mask, softmax over a (lanes 0..31 of wave 0) ----
    if (tid < A_DIM) {
        float m = (float)mask[bid * A_DIM + tid];
        float e = e1s + e2s[tid];
        e = (e >= 0.f) ? e : 0.2f * e;  // LeakyReLU(0.2)
        e *= m;                         // E_mask = E * m (masked -> 0, NOT -inf)
        float mx = e;
        mx = fmaxf(mx, __shfl_xor(mx, 16, 32));
        mx = fmaxf(mx, __shfl_xor(mx, 8, 32));
        mx = fmaxf(mx, __shfl_xor(mx, 4, 32));
        mx = fmaxf(mx, __shfl_xor(mx, 2, 32));
        mx = fmaxf(mx, __shfl_xor(mx, 1, 32));
        float ex = expf(e - mx);
        float sum = ex;
        sum += __shfl_xor(sum, 16, 32);
        sum += __shfl_xor(sum, 8, 32);
        sum += __shfl_xor(sum, 4, 32);
        sum += __shfl_xor(sum, 2, 32);
        sum += __shfl_xor(sum, 1, 32);
        coef[tid] = ex / sum * m;  // alpha * m
    }
    __syncthreads();

    // ---- wm[h] = sum_a coef[a]*msg[a][h];  U = h + wm ----
    if (tid < HID) {
        float acc = 0.f;
#pragma unroll
        for (int a = 0; a < A_DIM; ++a) acc += coef[a] * msg[a][tid];
        U[bid * HID + tid] = hv[tid] + acc;
    }
}

__global__ __launch_bounds__(256) void out_kernel(
    const float* __restrict__ U,
    const float* __restrict__ W,
    const float* __restrict__ ws,  // owT at +256
    const float* __restrict__ out_b,
    float* __restrict__ out) {
    __shared__ float u_lds[A_DIM][HID];   // 32 rows of U
    __shared__ float t1_lds[A_DIM][HID];  // t1 = Utile @ W

    const int tid = threadIdx.x;
    const int row0 = blockIdx.x * 32;

    const float4* gu = reinterpret_cast<const float4*>(U + (size_t)row0 * HID);
    float4* su = reinterpret_cast<float4*>(&u_lds[0][0]);
#pragma unroll
    for (int i = 0; i < 4; ++i) su[tid + i * 256] = gu[tid + i * 256];
    __syncthreads();

    const int c = tid & 127;  // column: h in phase 1, o in phase 2
    const int rg = tid >> 7;  // row-group 0/1 (16 rows each)

    float acc[16];
#pragma unroll
    for (int r = 0; r < 16; ++r) acc[r] = 0.f;
    for (int d = 0; d < HID; ++d) {
        float w = W[d * HID + c];  // coalesced; broadcast u_lds reads
#pragma unroll
        for (int r = 0; r < 16; ++r) acc[r] += u_lds[rg * 16 + r][d] * w;
    }
#pragma unroll
    for (int r = 0; r < 16; ++r) t1_lds[rg * 16 + r][c] = acc[r];
    __syncthreads();

    const float* owT = ws + 256;
#pragma unroll
    for (int r = 0; r < 16; ++r) acc[r] = 0.f;
    for (int hh = 0; hh < HID; ++hh) {
        float w = owT[hh * HID + c];  // coalesced (out_w transposed in k0)
#pragma unroll
        for (int r = 0; r < 16; ++r) acc[r] += t1_lds[rg * 16 + r][hh] * w;
    }
    const float b = out_b[c];
#pragma unroll
    for (int r = 0; r < 16; ++r) {
        float x = acc[r] + b;
        out[(size_t)(row0 + rg * 16 + r) * HID + c] = (x > 0.f) ? x : expm1f(x);
    }
}

extern "C" void kernel_launch(void* const* d_in, const int* in_sizes, int n_in,
                              void* d_out, int out_size, void* d_ws, size_t ws_size,
                              hipStream_t stream) {
    const float* hmat = (const float*)d_in[0];     // (256,32,128)
    const float* message = (const float*)d_in[1];  // (256,32,32,128)
    const int* mask = (const int*)d_in[2];         // (256,32,32)
    const float* W = (const float*)d_in[3];        // (128,128)
    const float* a_w = (const float*)d_in[4];      // (256,)
    const float* out_w = (const float*)d_in[5];    // (128,128)
    const float* out_b = (const float*)d_in[6];    // (128,)
    float* out = (float*)d_out;                    // (256,32,128) f32
    float* ws = (float*)d_ws;
    float* U = ws + 256 + HID * HID;

    precompute_kernel<<<1, 128, 0, stream>>>(W, a_w, out_w, ws);
    attn_kernel<<<8192, 256, 0, stream>>>(hmat, message, mask, ws, U);
    out_kernel<<<256, 256, 0, stream>>>(U, W, ws, out_b, out);
}

// Round 2
// 52.179 us; speedup vs baseline: 1.2636x; 1.2636x over previous
//
#include <hip/hip_runtime.h>
#include <cstdint>
#include <cstddef>

#define HID 128
#define A_DIM 32

// ws layout (floats):
//   [0, 128)            Wa1 = W @ a_w[:128]
//   [128, 256)          Wa2 = W @ a_w[128:]
//   [256, 256+16384)    P[d][o] = sum_h W[d][h] * out_w[o][h]   (= W @ out_w^T)
//   [16640, +8192*128)  U[b*32+n][:] = h[b,n,:] + wm[b,n,:]
// total ~4.26 MB

// 64 blocks x 256 threads: each thread one entry of P. Block 0 also does Wa1/Wa2.
__global__ __launch_bounds__(256) void precompute_kernel(
    const float* __restrict__ W,
    const float* __restrict__ a_w,
    const float* __restrict__ out_w,
    float* __restrict__ ws) {
    const int tid = threadIdx.x;
    const int g = blockIdx.x * 256 + tid;
    const int d = g >> 7, o = g & 127;
    const float4* W4 = reinterpret_cast<const float4*>(W);
    const float4* ow4 = reinterpret_cast<const float4*>(out_w);
    float p = 0.f;
#pragma unroll 8
    for (int j = 0; j < 32; ++j) {
        float4 wv = W4[d * 32 + j];   // broadcast across lanes with same d
        float4 ov = ow4[o * 32 + j];
        p += wv.x * ov.x + wv.y * ov.y + wv.z * ov.z + wv.w * ov.w;
    }
    ws[256 + d * HID + o] = p;

    if (blockIdx.x == 0) {
        // Wa1 (tid<128) / Wa2 (tid>=128)
        const int t = tid & 127;
        const float4* av = reinterpret_cast<const float4*>(a_w + (tid < 128 ? 0 : HID));
        float s = 0.f;
#pragma unroll 8
        for (int j = 0; j < 32; ++j) {
            float4 wv = W4[t * 32 + j];
            float4 va = av[j];
            s += wv.x * va.x + wv.y * va.y + wv.z * va.z + wv.w * va.w;
        }
        ws[tid] = s;
    }
}

// One block per (b,n). message tile lives in REGISTERS (4 float4 per thread);
// LDS only for tiny cross-wave reductions (4.4 KB, conflict-free).
__global__ __launch_bounds__(256) void attn_kernel(
    const float* __restrict__ hmat,
    const float* __restrict__ message,
    const int* __restrict__ mask,
    const float* __restrict__ ws,
    float* __restrict__ U) {
    __shared__ float e2s[A_DIM];
    __shared__ float coef[A_DIM];
    __shared__ float e1s;
    __shared__ float part[8][HID];  // 4 KB reduction buffer

    const int tid = threadIdx.x;
    const size_t bid = blockIdx.x;  // flattened (b,n)

    // ---- register staging: thread tid holds rows a_i=(tid>>5)+8i, cols (tid&31)*4.. ----
    const float4* gm = reinterpret_cast<const float4*>(message + bid * (A_DIM * HID));
    float4 v0 = gm[tid];
    float4 v1 = gm[tid + 256];
    float4 v2 = gm[tid + 512];
    float4 v3 = gm[tid + 768];

    float hreg = 0.f;
    if (tid < HID) hreg = hmat[bid * HID + tid];

    const float4* wa2v = reinterpret_cast<const float4*>(ws + HID);
    float4 w2 = wa2v[tid & 31];

    // ---- e2 partials from registers; reduce within each 32-lane group ----
    float p0 = v0.x * w2.x + v0.y * w2.y + v0.z * w2.z + v0.w * w2.w;
    float p1 = v1.x * w2.x + v1.y * w2.y + v1.z * w2.z + v1.w * w2.w;
    float p2 = v2.x * w2.x + v2.y * w2.y + v2.z * w2.z + v2.w * w2.w;
    float p3 = v3.x * w2.x + v3.y * w2.y + v3.z * w2.z + v3.w * w2.w;
#pragma unroll
    for (int m = 16; m >= 1; m >>= 1) {
        p0 += __shfl_xor(p0, m);
        p1 += __shfl_xor(p1, m);
        p2 += __shfl_xor(p2, m);
        p3 += __shfl_xor(p3, m);
    }
    if ((tid & 31) == 0) {
        const int a = tid >> 5;
        e2s[a] = p0;
        e2s[a + 8] = p1;
        e2s[a + 16] = p2;
        e2s[a + 24] = p3;
    }

    // ---- e1 = dot(h, Wa1) by wave 0 ----
    if (tid < 64) {
        float hb = hmat[bid * HID + 64 + tid];  // L1 hit (just fetched above)
        float p = hreg * ws[tid] + hb * ws[64 + tid];
        p += __shfl_down(p, 32);
        p += __shfl_down(p, 16);
        p += __shfl_down(p, 8);
        p += __shfl_down(p, 4);
        p += __shfl_down(p, 2);
        p += __shfl_down(p, 1);
        if (tid == 0) e1s = p;
    }
    __syncthreads();

    // ---- leaky-relu, mask, softmax over a (lanes 0..31) ----
    if (tid < A_DIM) {
        float m = (float)mask[bid * A_DIM + tid];
        float e = e1s + e2s[tid];
        e = (e >= 0.f) ? e : 0.2f * e;  // LeakyReLU(0.2)
        e *= m;                         // E_mask (masked -> 0, not -inf)
        float mx = e;
        mx = fmaxf(mx, __shfl_xor(mx, 16));
        mx = fmaxf(mx, __shfl_xor(mx, 8));
        mx = fmaxf(mx, __shfl_xor(mx, 4));
        mx = fmaxf(mx, __shfl_xor(mx, 2));
        mx = fmaxf(mx, __shfl_xor(mx, 1));
        float ex = __expf(e - mx);
        float sum = ex;
        sum += __shfl_xor(sum, 16);
        sum += __shfl_xor(sum, 8);
        sum += __shfl_xor(sum, 4);
        sum += __shfl_xor(sum, 2);
        sum += __shfl_xor(sum, 1);
        coef[tid] = ex / sum * m;  // alpha * m
    }
    __syncthreads();

    // ---- weighted message sum from registers ----
    {
        const int a = tid >> 5;
        const float c0 = coef[a];         // broadcast LDS reads
        const float c1 = coef[a + 8];
        const float c2 = coef[a + 16];
        const float c3 = coef[a + 24];
        float4 pw;
        pw.x = c0 * v0.x + c1 * v1.x + c2 * v2.x + c3 * v3.x;
        pw.y = c0 * v0.y + c1 * v1.y + c2 * v2.y + c3 * v3.y;
        pw.z = c0 * v0.z + c1 * v1.z + c2 * v2.z + c3 * v3.z;
        pw.w = c0 * v0.w + c1 * v1.w + c2 * v2.w + c3 * v3.w;
        reinterpret_cast<float4*>(&part[a][0])[tid & 31] = pw;
    }
    __syncthreads();

    if (tid < HID) {
        float s = hreg;
#pragma unroll
        for (int g = 0; g < 8; ++g) s += part[g][tid];  // bank = tid%32: 2-way, free
        U[bid * HID + tid] = s;
    }
}

// out = elu(U @ P + b), 16 rows per block.
__global__ __launch_bounds__(256) void out_kernel(
    const float* __restrict__ U,
    const float* __restrict__ ws,
    const float* __restrict__ out_b,
    float* __restrict__ out) {
    const float* P = ws + 256;
    __shared__ float u_lds[16][HID];  // 8 KB

    const int tid = threadIdx.x;
    const size_t row0 = (size_t)blockIdx.x * 16;

    const float4* gu = reinterpret_cast<const float4*>(U + row0 * HID);
    float4* su = reinterpret_cast<float4*>(&u_lds[0][0]);
    su[tid] = gu[tid];
    su[tid + 256] = gu[tid + 256];
    __syncthreads();

    const int c = tid & 127;  // output column o
    const int rg = tid >> 7;  // row group (8 rows each)

    float acc[8];
#pragma unroll
    for (int r = 0; r < 8; ++r) acc[r] = 0.f;
    for (int d = 0; d < HID; ++d) {
        float w = P[d * HID + c];  // coalesced, L2-resident
#pragma unroll
        for (int r = 0; r < 8; ++r) acc[r] += u_lds[rg * 8 + r][d] * w;  // broadcast
    }
    const float b = out_b[c];
#pragma unroll
    for (int r = 0; r < 8; ++r) {
        float x = acc[r] + b;
        out[(row0 + rg * 8 + r) * HID + c] = (x > 0.f) ? x : expm1f(x);
    }
}

extern "C" void kernel_launch(void* const* d_in, const int* in_sizes, int n_in,
                              void* d_out, int out_size, void* d_ws, size_t ws_size,
                              hipStream_t stream) {
    const float* hmat = (const float*)d_in[0];     // (256,32,128)
    const float* message = (const float*)d_in[1];  // (256,32,32,128)
    const int* mask = (const int*)d_in[2];         // (256,32,32)
    const float* W = (const float*)d_in[3];        // (128,128)
    const float* a_w = (const float*)d_in[4];      // (256,)
    const float* out_w = (const float*)d_in[5];    // (128,128)
    const float* out_b = (const float*)d_in[6];    // (128,)
    float* out = (float*)d_out;                    // (256,32,128) f32
    float* ws = (float*)d_ws;
    float* U = ws + 256 + HID * HID;

    precompute_kernel<<<64, 256, 0, stream>>>(W, a_w, out_w, ws);
    attn_kernel<<<8192, 256, 0, stream>>>(hmat, message, mask, ws, U);
    out_kernel<<<512, 256, 0, stream>>>(U, ws, out_b, out);
}

// Round 3
// 45.003 us; speedup vs baseline: 1.4652x; 1.1595x over previous
//
#include <hip/hip_runtime.h>
#include <cstdint>
#include <cstddef>

#define HID 128
#define A_DIM 32

// ws layout (floats):
//   [0, 128)            Wa1 = W @ a_w[:128]
//   [128, 256)          Wa2 = W @ a_w[128:]
//   [256, 256+16384)    P[d][o] = sum_h W[d][h]*out_w[o][h]  (= W @ out_w^T)
//   [16640, +8192*128)  U[(b,i)][:] = h + weighted_msg_sum
// total ~4.26 MB

// ---- k0: Wa1/Wa2 (8 blocks). 8 threads per output row. ----
__global__ __launch_bounds__(256) void wa_kernel(const float* __restrict__ W,
                                                 const float* __restrict__ a_w,
                                                 float* __restrict__ ws) {
    const int tid = threadIdx.x;
    const int s = blockIdx.x * 32 + (tid >> 3);  // 0..255 (0-127: Wa1, 128-255: Wa2)
    const int p8 = tid & 7;
    const int row = s & 127, which = s >> 7;
    const float4* W4 = reinterpret_cast<const float4*>(W);
    const float4* av = reinterpret_cast<const float4*>(a_w + which * HID);
    float p = 0.f;
#pragma unroll
    for (int i = 0; i < 4; ++i) {
        float4 wv = W4[row * 32 + p8 * 4 + i];
        float4 va = av[p8 * 4 + i];
        p += wv.x * va.x + wv.y * va.y + wv.z * va.z + wv.w * va.w;
    }
    p += __shfl_down(p, 4);
    p += __shfl_down(p, 2);
    p += __shfl_down(p, 1);
    if (p8 == 0) ws[s] = p;
}

// ---- k1: blocks 0..63 compute P; blocks 64.. are attention, ONE WAVE per
// (b,i) pair, zero barriers (wave-synchronous). ----
__global__ __launch_bounds__(256, 4) void attn_kernel(
    const float* __restrict__ hmat,
    const float* __restrict__ message,
    const int* __restrict__ mask,
    const float* __restrict__ W,
    const float* __restrict__ out_w,
    float* __restrict__ ws,
    float* __restrict__ U) {
    const int tid = threadIdx.x;

    if (blockIdx.x < 64) {  // ---- P = W @ out_w^T (no ordering deps: reads inputs only) ----
        const int g = blockIdx.x * 256 + tid;
        const int d = g >> 7, o = g & 127;
        const float4* W4 = reinterpret_cast<const float4*>(W);
        const float4* ow4 = reinterpret_cast<const float4*>(out_w);
        float p = 0.f;
#pragma unroll 8
        for (int j = 0; j < 32; ++j) {
            float4 wv = W4[d * 32 + j];   // broadcast within wave
            float4 ov = ow4[o * 32 + j];  // gather, L2-resident after first touch
            p += wv.x * ov.x + wv.y * ov.y + wv.z * ov.z + wv.w * ov.w;
        }
        ws[256 + d * HID + o] = p;
        return;
    }

    __shared__ float red[4][A_DIM][33];  // per-wave padded partial buffer
    __shared__ float cf[4][A_DIM];       // per-wave coefficients

    const int w = tid >> 6;        // wave in block
    const int lane = tid & 63;
    const int half = lane >> 5;    // 0/1
    const int q = lane & 31;
    const size_t bid = (size_t)(blockIdx.x - 64) * 4 + w;  // (b,i) pair, 0..8191

    // ---- issue all loads up front ----
    const float4* gm4 = reinterpret_cast<const float4*>(message) + bid * (A_DIM * HID / 4);
    float4 v[16];  // rows 2i+half, cols 4q..4q+3
#pragma unroll
    for (int i = 0; i < 16; ++i) v[i] = gm4[(2 * i + half) * 32 + q];
    const float4* ws4 = reinterpret_cast<const float4*>(ws);
    float4 w1 = ws4[q];        // Wa1 cols 4q..
    float4 w2 = ws4[32 + q];   // Wa2 cols 4q..
    float4 h4 = (reinterpret_cast<const float4*>(hmat) + bid * 32)[q];
    float mv = (float)mask[bid * A_DIM + q];  // mask for row q

    // ---- e1 = dot(h, Wa1): half0 contributes, 6-level butterfly (overlaps v loads) ----
    float pe1 = (half == 0) ? (h4.x * w1.x + h4.y * w1.y + h4.z * w1.z + h4.w * w1.w) : 0.f;
#pragma unroll
    for (int m = 32; m >= 1; m >>= 1) pe1 += __shfl_xor(pe1, m);

    // ---- e2 partials -> LDS (conflict-free via +1 pad) ----
#pragma unroll
    for (int i = 0; i < 16; ++i) {
        float p2 = v[i].x * w2.x + v[i].y * w2.y + v[i].z * w2.z + v[i].w * w2.w;
        red[w][2 * i + half][q] = p2;
    }
    // lane handles row q: sum its 16-entry slice, then pair-combine across halves
    float e2 = 0.f;
#pragma unroll
    for (int k = 0; k < 16; ++k) e2 += red[w][q][16 * half + k];
    e2 += __shfl_xor(e2, 32);

    // ---- E, leaky-relu, mask, softmax over rows (both halves duplicate) ----
    float e = pe1 + e2;
    e = (e >= 0.f) ? e : 0.2f * e;  // LeakyReLU(0.2)
    e *= mv;                        // E_mask (masked -> 0, not -inf)
    float mx = e;
#pragma unroll
    for (int m = 16; m >= 1; m >>= 1) mx = fmaxf(mx, __shfl_xor(mx, m));
    float ex = __expf(e - mx);
    float sum = ex;
#pragma unroll
    for (int m = 16; m >= 1; m >>= 1) sum += __shfl_xor(sum, m);
    float coef = ex / sum * mv;  // alpha * m for row q
    cf[w][q] = coef;             // both halves write same value — benign

    // ---- weighted message sum from registers (coef via LDS broadcast reads) ----
    float4 acc = {0.f, 0.f, 0.f, 0.f};
#pragma unroll
    for (int i = 0; i < 16; ++i) {
        float c = cf[w][2 * i + half];
        acc.x += c * v[i].x;
        acc.y += c * v[i].y;
        acc.z += c * v[i].z;
        acc.w += c * v[i].w;
    }
    acc.x += __shfl_xor(acc.x, 32);
    acc.y += __shfl_xor(acc.y, 32);
    acc.z += __shfl_xor(acc.z, 32);
    acc.w += __shfl_xor(acc.w, 32);

    if (half == 0) {
        float4 u;
        u.x = h4.x + acc.x;
        u.y = h4.y + acc.y;
        u.z = h4.z + acc.z;
        u.w = h4.w + acc.w;
        reinterpret_cast<float4*>(U)[bid * 32 + q] = u;
    }
}

// ---- k2: out = elu(U @ P + b). 16 rows/block, float4 everywhere. ----
__global__ __launch_bounds__(256) void out_kernel(
    const float* __restrict__ U,
    const float* __restrict__ ws,
    const float* __restrict__ out_b,
    float* __restrict__ out) {
    const float* P = ws + 256;
    __shared__ float u_lds[16][132];  // +4 pad: conflict-free b128 broadcast reads

    const int tid = threadIdx.x;
    const size_t row0 = (size_t)blockIdx.x * 16;
    const float4* gu = reinterpret_cast<const float4*>(U + row0 * HID);
#pragma unroll
    for (int i = 0; i < 2; ++i) {
        int idx = tid + i * 256;  // 0..511
        int r = idx >> 5, c4 = idx & 31;
        float4 vv = gu[idx];
        *reinterpret_cast<float4*>(&u_lds[r][c4 * 4]) = vv;
    }
    __syncthreads();

    const int tx = tid & 31;   // col group: cols 4tx..4tx+3
    const int ty = tid >> 5;   // rows 2ty, 2ty+1
    const float4* P4 = reinterpret_cast<const float4*>(P);

    float4 a0 = {0.f, 0.f, 0.f, 0.f}, a1 = {0.f, 0.f, 0.f, 0.f};
    for (int kg = 0; kg < 32; ++kg) {
        float4 p0 = P4[(4 * kg + 0) * 32 + tx];
        float4 p1 = P4[(4 * kg + 1) * 32 + tx];
        float4 p2 = P4[(4 * kg + 2) * 32 + tx];
        float4 p3 = P4[(4 * kg + 3) * 32 + tx];
        float4 u0 = *reinterpret_cast<const float4*>(&u_lds[2 * ty][4 * kg]);      // broadcast
        float4 u1 = *reinterpret_cast<const float4*>(&u_lds[2 * ty + 1][4 * kg]);  // broadcast
        a0.x += u0.x * p0.x + u0.y * p1.x + u0.z * p2.x + u0.w * p3.x;
        a0.y += u0.x * p0.y + u0.y * p1.y + u0.z * p2.y + u0.w * p3.y;
        a0.z += u0.x * p0.z + u0.y * p1.z + u0.z * p2.z + u0.w * p3.z;
        a0.w += u0.x * p0.w + u0.y * p1.w + u0.z * p2.w + u0.w * p3.w;
        a1.x += u1.x * p0.x + u1.y * p1.x + u1.z * p2.x + u1.w * p3.x;
        a1.y += u1.x * p0.y + u1.y * p1.y + u1.z * p2.y + u1.w * p3.y;
        a1.z += u1.x * p0.z + u1.y * p1.z + u1.z * p2.z + u1.w * p3.z;
        a1.w += u1.x * p0.w + u1.y * p1.w + u1.z * p2.w + u1.w * p3.w;
    }
    float4 b4 = reinterpret_cast<const float4*>(out_b)[tx];
    float4 o0, o1;
    float x;
    x = a0.x + b4.x; o0.x = (x > 0.f) ? x : expm1f(x);
    x = a0.y + b4.y; o0.y = (x > 0.f) ? x : expm1f(x);
    x = a0.z + b4.z; o0.z = (x > 0.f) ? x : expm1f(x);
    x = a0.w + b4.w; o0.w = (x > 0.f) ? x : expm1f(x);
    x = a1.x + b4.x; o1.x = (x > 0.f) ? x : expm1f(x);
    x = a1.y + b4.y; o1.y = (x > 0.f) ? x : expm1f(x);
    x = a1.z + b4.z; o1.z = (x > 0.f) ? x : expm1f(x);
    x = a1.w + b4.w; o1.w = (x > 0.f) ? x : expm1f(x);
    float4* out4 = reinterpret_cast<float4*>(out);
    out4[(row0 + 2 * ty) * 32 + tx] = o0;
    out4[(row0 + 2 * ty + 1) * 32 + tx] = o1;
}

extern "C" void kernel_launch(void* const* d_in, const int* in_sizes, int n_in,
                              void* d_out, int out_size, void* d_ws, size_t ws_size,
                              hipStream_t stream) {
    const float* hmat = (const float*)d_in[0];     // (256,32,128)
    const float* message = (const float*)d_in[1];  // (256,32,32,128)
    const int* mask = (const int*)d_in[2];         // (256,32,32)
    const float* W = (const float*)d_in[3];        // (128,128)
    const float* a_w = (const float*)d_in[4];      // (256,)
    const float* out_w = (const float*)d_in[5];    // (128,128)
    const float* out_b = (const float*)d_in[6];    // (128,)
    float* out = (float*)d_out;                    // (256,32,128) f32
    float* ws = (float*)d_ws;
    float* U = ws + 256 + HID * HID;

    wa_kernel<<<8, 256, 0, stream>>>(W, a_w, ws);
    attn_kernel<<<64 + 2048, 256, 0, stream>>>(hmat, message, mask, W, out_w, ws, U);
    out_kernel<<<512, 256, 0, stream>>>(U, ws, out_b, out);
}